// Round 1
// baseline (289.660 us; speedup 1.0000x reference)
//
#include <hip/hip_runtime.h>
#include <stdint.h>

#define NB 32
#define NL 1024
#define ND 256

typedef __attribute__((ext_vector_type(8))) __bf16 bf16x8;
typedef __attribute__((ext_vector_type(4))) float f32x4;

__device__ __forceinline__ uint16_t f2bf(float f) {
  union { float f; uint32_t u; } v; v.f = f;
  return (uint16_t)((v.u + 0x7fffu + ((v.u >> 16) & 1u)) >> 16);
}

// async global->LDS, 16B per lane. LDS dest is wave-uniform base + lane*16.
#define GLD_LDS16(g, l)                                                        \
  __builtin_amdgcn_global_load_lds(                                            \
      (__attribute__((address_space(1))) void*)(g),                            \
      (__attribute__((address_space(3))) void*)(l), 16, 0, 0)

// ---------------------------------------------------------------------------
// Kernel 0: q fp32 -> Qb bf16 [b][l][d]  and  Qt bf16 [b][d][l] (transposed)
// ---------------------------------------------------------------------------
__global__ __launch_bounds__(256) void convert_kernel(
    const float* __restrict__ q, uint16_t* __restrict__ qb,
    uint16_t* __restrict__ qt) {
  __shared__ uint16_t tile[64][72];  // +8 pad to break transpose conflicts
  int b = blockIdx.z;
  int l0 = blockIdx.x * 64, d0 = blockIdx.y * 64;
  int t = threadIdx.x;
  int r = t >> 4;          // 0..15
  int c4 = (t & 15) * 4;   // 0..60
  const float* qsrc = q + (size_t)b * NL * ND;
  uint16_t* qbb = qb + (size_t)b * NL * ND;
  uint16_t* qtb = qt + (size_t)b * ND * NL;
#pragma unroll
  for (int i = 0; i < 4; i++) {
    int row = r + 16 * i;
    float4 v = *(const float4*)(qsrc + (size_t)(l0 + row) * ND + d0 + c4);
    ushort4 h;
    h.x = f2bf(v.x); h.y = f2bf(v.y); h.z = f2bf(v.z); h.w = f2bf(v.w);
    *(ushort4*)(qbb + (size_t)(l0 + row) * ND + d0 + c4) = h;
    tile[row][c4 + 0] = h.x; tile[row][c4 + 1] = h.y;
    tile[row][c4 + 2] = h.z; tile[row][c4 + 3] = h.w;
  }
  __syncthreads();
#pragma unroll
  for (int i = 0; i < 4; i++) {
    int drow = r + 16 * i;  // local d
    ushort4 h;
    h.x = tile[c4 + 0][drow]; h.y = tile[c4 + 1][drow];
    h.z = tile[c4 + 2][drow]; h.w = tile[c4 + 3][drow];
    *(ushort4*)(qtb + (size_t)(d0 + drow) * NL + l0 + c4) = h;
  }
}

// ---------------------------------------------------------------------------
// Kernel 1: E[b][m][n] = exp(S/16), S = Qb Qb^T   (unnormalized; s==0 -> 0)
// gemm_bt, 128x128 tile, BK=32, 4 waves in 2x2, each wave 64x64 (4x4 MFMA)
// ---------------------------------------------------------------------------
__global__ __launch_bounds__(256) void qk_kernel(
    const uint16_t* __restrict__ qb, float* __restrict__ e_out) {
  __shared__ alignas(16) uint16_t As[128 * 32];
  __shared__ alignas(16) uint16_t Bs[128 * 32];
  int b = blockIdx.z;
  int m0 = blockIdx.x * 128, n0 = blockIdx.y * 128;
  const uint16_t* Q = qb + (size_t)b * NL * ND;
  int tid = threadIdx.x, lane = tid & 63, wave = tid >> 6;
  int wm = (wave & 1) * 64, wn = (wave >> 1) * 64;
  int quad = lane >> 4, l15 = lane & 15;
  f32x4 acc[4][4] = {};

  for (int k0 = 0; k0 < ND; k0 += 32) {
    __syncthreads();
#pragma unroll
    for (int i = 0; i < 2; i++) {
      int c = i * 256 + wave * 64 + lane;   // chunk id, 16B chunks
      int row = c >> 2, cc = c & 3;
      int sw = (row >> 1) & 3;              // xor swizzle -> 2-way (free) LDS reads
      int gc = k0 + ((cc ^ sw) * 8);
      GLD_LDS16(Q + (size_t)(m0 + row) * ND + gc,
                As + (size_t)(i * 256 + wave * 64) * 8);
      GLD_LDS16(Q + (size_t)(n0 + row) * ND + gc,
                Bs + (size_t)(i * 256 + wave * 64) * 8);
    }
    __syncthreads();
    bf16x8 af[4], bfr[4];
#pragma unroll
    for (int t = 0; t < 4; t++) {
      int ra = wm + t * 16 + l15;
      af[t] = *(const bf16x8*)(As + ra * 32 + ((quad ^ ((ra >> 1) & 3)) * 8));
      int rb = wn + t * 16 + l15;
      bfr[t] = *(const bf16x8*)(Bs + rb * 32 + ((quad ^ ((rb >> 1) & 3)) * 8));
    }
#pragma unroll
    for (int tm = 0; tm < 4; tm++)
#pragma unroll
      for (int tn = 0; tn < 4; tn++)
        acc[tm][tn] = __builtin_amdgcn_mfma_f32_16x16x32_bf16(
            af[tm], bfr[tn], acc[tm][tn], 0, 0, 0);
  }

  // epilogue: e = (s==0) ? 0 : exp2(s * log2(e)/16); C/D: col=lane&15, row=quad*4+j
  const float k = 0.09016844005555f;  // log2(e)/16
  float* Eb = e_out + (size_t)b * NL * NL;
#pragma unroll
  for (int tm = 0; tm < 4; tm++) {
    int rbase = m0 + wm + tm * 16 + quad * 4;
#pragma unroll
    for (int tn = 0; tn < 4; tn++) {
      int col = n0 + wn + tn * 16 + l15;
#pragma unroll
      for (int j = 0; j < 4; j++) {
        float s = acc[tm][tn][j];
        float e = (s == 0.0f) ? 0.0f : __builtin_amdgcn_exp2f(s * k);
        Eb[(size_t)(rbase + j) * NL + col] = e;
      }
    }
  }
}

// ---------------------------------------------------------------------------
// Kernel 2: per-row sum + in-place normalize (handles all-zero row -> zeros)
// one block per (b,l) row of 1024
// ---------------------------------------------------------------------------
__global__ __launch_bounds__(256) void norm_kernel(float* __restrict__ attn) {
  __shared__ float red[4];
  float* p = attn + (size_t)blockIdx.x * NL;
  int t = threadIdx.x;
  float4 v = *(float4*)(p + t * 4);
  float s = v.x + v.y + v.z + v.w;
#pragma unroll
  for (int off = 32; off > 0; off >>= 1) s += __shfl_down(s, off, 64);
  int wave = t >> 6, lane = t & 63;
  if (lane == 0) red[wave] = s;
  __syncthreads();
  float total = red[0] + red[1] + red[2] + red[3];
  float inv = (total > 0.0f) ? 1.0f / total : 0.0f;
  v.x *= inv; v.y *= inv; v.z *= inv; v.w *= inv;
  *(float4*)(p + t * 4) = v;
}

// ---------------------------------------------------------------------------
// Kernel 3: out = P @ Q  = gemm_bt(P, Qt).  A = fp32 P (cvt->bf16 in staging),
// B = Qt bf16 via global_load_lds. Tile 128x128, K=1024, BK=32.
// ---------------------------------------------------------------------------
__global__ __launch_bounds__(256) void pv_kernel(
    const float* __restrict__ attn, const uint16_t* __restrict__ qt,
    float* __restrict__ out) {
  __shared__ alignas(16) uint16_t As[128 * 40];  // padded stride 40 (free reads)
  __shared__ alignas(16) uint16_t Bs[128 * 32];
  int b = blockIdx.z;
  int m0 = blockIdx.x * 128, d0 = blockIdx.y * 128;
  const float* A = attn + (size_t)b * NL * NL;
  const uint16_t* Bt = qt + (size_t)b * ND * NL;
  int tid = threadIdx.x, lane = tid & 63, wave = tid >> 6;
  int wm = (wave & 1) * 64, wn = (wave >> 1) * 64;
  int quad = lane >> 4, l15 = lane & 15;
  f32x4 acc[4][4] = {};

  for (int k0 = 0; k0 < NL; k0 += 32) {
    __syncthreads();
#pragma unroll
    for (int i = 0; i < 2; i++) {
      int c = i * 256 + wave * 64 + lane;
      int row = c >> 2, cc = c & 3;
      int sw = (row >> 1) & 3;
      GLD_LDS16(Bt + (size_t)(d0 + row) * NL + k0 + ((cc ^ sw) * 8),
                Bs + (size_t)(i * 256 + wave * 64) * 8);
    }
#pragma unroll
    for (int j = 0; j < 4; j++) {
      int f = tid + j * 256;
      int row = f >> 3, c4 = (f & 7) * 4;
      float4 v = *(const float4*)(A + (size_t)(m0 + row) * NL + k0 + c4);
      ushort4 h;
      h.x = f2bf(v.x); h.y = f2bf(v.y); h.z = f2bf(v.z); h.w = f2bf(v.w);
      *(ushort4*)(&As[row * 40 + c4]) = h;
    }
    __syncthreads();
    bf16x8 af[4], bfr[4];
#pragma unroll
    for (int t = 0; t < 4; t++) {
      int ra = wm + t * 16 + l15;
      af[t] = *(const bf16x8*)(&As[ra * 40 + quad * 8]);
      int rb = wn + t * 16 + l15;
      bfr[t] = *(const bf16x8*)(&Bs[rb * 32 + ((quad ^ ((rb >> 1) & 3)) * 8)]);
    }
#pragma unroll
    for (int tm = 0; tm < 4; tm++)
#pragma unroll
      for (int tn = 0; tn < 4; tn++)
        acc[tm][tn] = __builtin_amdgcn_mfma_f32_16x16x32_bf16(
            af[tm], bfr[tn], acc[tm][tn], 0, 0, 0);
  }

  float* O = out + (size_t)b * NL * ND;
#pragma unroll
  for (int tm = 0; tm < 4; tm++) {
    int rbase = m0 + wm + tm * 16 + quad * 4;
#pragma unroll
    for (int tn = 0; tn < 4; tn++) {
      int col = d0 + wn + tn * 16 + l15;
#pragma unroll
      for (int j = 0; j < 4; j++)
        O[(size_t)(rbase + j) * ND + col] = acc[tm][tn][j];
    }
  }
}

// ---------------------------------------------------------------------------
extern "C" void kernel_launch(void* const* d_in, const int* in_sizes, int n_in,
                              void* d_out, int out_size, void* d_ws,
                              size_t ws_size, hipStream_t stream) {
  (void)in_sizes; (void)n_in; (void)out_size; (void)ws_size;
  const float* q = (const float*)d_in[0];
  float* out = (float*)d_out;
  float* attn = out + (size_t)NB * NL * ND;      // outputs concat: [output | attn]
  uint16_t* qb = (uint16_t*)d_ws;                // 16 MB
  uint16_t* qt = qb + (size_t)NB * NL * ND;      // 16 MB

  convert_kernel<<<dim3(16, 4, NB), 256, 0, stream>>>(q, qb, qt);
  qk_kernel<<<dim3(8, 8, NB), 256, 0, stream>>>(qb, attn);
  norm_kernel<<<NB * NL, 256, 0, stream>>>(attn);
  pv_kernel<<<dim3(8, 2, NB), 256, 0, stream>>>(attn, qt, out);
}

// Round 2
// 271.097 us; speedup vs baseline: 1.0685x; 1.0685x over previous
//
#include <hip/hip_runtime.h>
#include <stdint.h>

#define NB 32
#define NL 1024
#define ND 256
// attn fp32 row = 1024 f32 = 4096 B = 2048 u16 slots. Pack bf16 P in slots
// [0,1024); per-row partial sums (8 n-blocks) live in f32 slots [512,520).
#define ROWU16 2048

typedef __attribute__((ext_vector_type(8))) __bf16 bf16x8;
typedef __attribute__((ext_vector_type(4))) float f32x4;

__device__ __forceinline__ uint16_t f2bf(float f) {
  union { float f; uint32_t u; } v; v.f = f;
  return (uint16_t)((v.u + 0x7fffu + ((v.u >> 16) & 1u)) >> 16);
}
__device__ __forceinline__ float bf2f(uint16_t h) {
  union { uint32_t u; float f; } v; v.u = ((uint32_t)h) << 16;
  return v.f;
}

#define GLD_LDS16(g, l)                                                        \
  __builtin_amdgcn_global_load_lds(                                            \
      (__attribute__((address_space(1))) void*)(g),                            \
      (__attribute__((address_space(3))) void*)(l), 16, 0, 0)

// ---------------------------------------------------------------------------
// Kernel 0: q fp32 -> Qb bf16 [b][l][d]  and  Qt bf16 [b][d][l]
// ---------------------------------------------------------------------------
__global__ __launch_bounds__(256) void convert_kernel(
    const float* __restrict__ q, uint16_t* __restrict__ qb,
    uint16_t* __restrict__ qt) {
  __shared__ uint16_t tile[64][72];
  int b = blockIdx.z;
  int l0 = blockIdx.x * 64, d0 = blockIdx.y * 64;
  int t = threadIdx.x;
  int r = t >> 4;
  int c4 = (t & 15) * 4;
  const float* qsrc = q + (size_t)b * NL * ND;
  uint16_t* qbb = qb + (size_t)b * NL * ND;
  uint16_t* qtb = qt + (size_t)b * ND * NL;
#pragma unroll
  for (int i = 0; i < 4; i++) {
    int row = r + 16 * i;
    float4 v = *(const float4*)(qsrc + (size_t)(l0 + row) * ND + d0 + c4);
    ushort4 h;
    h.x = f2bf(v.x); h.y = f2bf(v.y); h.z = f2bf(v.z); h.w = f2bf(v.w);
    *(ushort4*)(qbb + (size_t)(l0 + row) * ND + d0 + c4) = h;
    tile[row][c4 + 0] = h.x; tile[row][c4 + 1] = h.y;
    tile[row][c4 + 2] = h.z; tile[row][c4 + 3] = h.w;
  }
  __syncthreads();
#pragma unroll
  for (int i = 0; i < 4; i++) {
    int drow = r + 16 * i;
    ushort4 h;
    h.x = tile[c4 + 0][drow]; h.y = tile[c4 + 1][drow];
    h.z = tile[c4 + 2][drow]; h.w = tile[c4 + 3][drow];
    *(ushort4*)(qtb + (size_t)(d0 + drow) * NL + l0 + c4) = h;
  }
}

// ---------------------------------------------------------------------------
// Kernel 1: e = exp(S/16) (s==0 -> 0), S = Qb Qb^T. Writes bf16 e packed into
// attn rows + per-(row, n-block) fp32 partial sums into spare slots.
// ---------------------------------------------------------------------------
__global__ __launch_bounds__(256) void qk_kernel(
    const uint16_t* __restrict__ qb, float* __restrict__ attn_f32) {
  __shared__ alignas(16) uint16_t As[128 * 32];
  __shared__ alignas(16) uint16_t Bs[128 * 32];
  __shared__ float rp[128][2];
  int b = blockIdx.z;
  int m0 = blockIdx.x * 128, n0 = blockIdx.y * 128;
  const uint16_t* Q = qb + (size_t)b * NL * ND;
  int tid = threadIdx.x, lane = tid & 63, wave = tid >> 6;
  int wm = (wave & 1) * 64, wn = (wave >> 1) * 64;
  int quad = lane >> 4, l15 = lane & 15;
  f32x4 acc[4][4] = {};

  for (int k0 = 0; k0 < ND; k0 += 32) {
    __syncthreads();
#pragma unroll
    for (int i = 0; i < 2; i++) {
      int c = i * 256 + wave * 64 + lane;
      int row = c >> 2, cc = c & 3;
      int sw = (row >> 1) & 3;
      int gc = k0 + ((cc ^ sw) * 8);
      GLD_LDS16(Q + (size_t)(m0 + row) * ND + gc,
                As + (size_t)(i * 256 + wave * 64) * 8);
      GLD_LDS16(Q + (size_t)(n0 + row) * ND + gc,
                Bs + (size_t)(i * 256 + wave * 64) * 8);
    }
    __syncthreads();
    bf16x8 af[4], bfr[4];
#pragma unroll
    for (int t = 0; t < 4; t++) {
      int ra = wm + t * 16 + l15;
      af[t] = *(const bf16x8*)(As + ra * 32 + ((quad ^ ((ra >> 1) & 3)) * 8));
      int rb = wn + t * 16 + l15;
      bfr[t] = *(const bf16x8*)(Bs + rb * 32 + ((quad ^ ((rb >> 1) & 3)) * 8));
    }
#pragma unroll
    for (int tm = 0; tm < 4; tm++)
#pragma unroll
      for (int tn = 0; tn < 4; tn++)
        acc[tm][tn] = __builtin_amdgcn_mfma_f32_16x16x32_bf16(
            af[tm], bfr[tn], acc[tm][tn], 0, 0, 0);
  }

  const float kf = 0.09016844005555f;  // log2(e)/16
  uint16_t* attn_u16 = (uint16_t*)attn_f32;
  size_t gbase = (size_t)b * NL;
#pragma unroll
  for (int tm = 0; tm < 4; tm++) {
    int rbl = wm + tm * 16 + quad * 4;  // local row base (j adds 0..3)
    float rsum[4] = {0.f, 0.f, 0.f, 0.f};
#pragma unroll
    for (int tn = 0; tn < 4; tn++) {
      int col = n0 + wn + tn * 16 + l15;
#pragma unroll
      for (int j = 0; j < 4; j++) {
        float s = acc[tm][tn][j];
        float e = (s == 0.0f) ? 0.0f : __builtin_amdgcn_exp2f(s * kf);
        attn_u16[(gbase + m0 + rbl + j) * ROWU16 + col] = f2bf(e);
        rsum[j] += e;
      }
    }
#pragma unroll
    for (int j = 0; j < 4; j++) {
      float v = rsum[j];
      v += __shfl_xor(v, 1, 64);
      v += __shfl_xor(v, 2, 64);
      v += __shfl_xor(v, 4, 64);
      v += __shfl_xor(v, 8, 64);
      if (l15 == 0) rp[rbl + j][wave >> 1] = v;
    }
  }
  __syncthreads();
  if (tid < 128) {
    float s = rp[tid][0] + rp[tid][1];
    attn_f32[(gbase + m0 + tid) * (size_t)NL + 512 + blockIdx.y] = s;
  }
}

// ---------------------------------------------------------------------------
// Kernel 2: out = (P @ Q) * inv_rowsum.  A = packed bf16 P (stride ROWU16),
// B = Qt bf16. Both via global_load_lds. Tile 128x128, K=1024, BK=32.
// ---------------------------------------------------------------------------
__global__ __launch_bounds__(256) void pv_kernel(
    const float* __restrict__ attn_f32, const uint16_t* __restrict__ qt,
    float* __restrict__ out) {
  __shared__ alignas(16) uint16_t As[128 * 32];
  __shared__ alignas(16) uint16_t Bs[128 * 32];
  __shared__ float inv_lds[128];
  int b = blockIdx.z;
  int m0 = blockIdx.x * 128, d0 = blockIdx.y * 128;
  const uint16_t* Ap = (const uint16_t*)attn_f32 + (size_t)b * NL * ROWU16;
  const uint16_t* Bt = qt + (size_t)b * ND * NL;
  int tid = threadIdx.x, lane = tid & 63, wave = tid >> 6;
  int wm = (wave & 1) * 64, wn = (wave >> 1) * 64;
  int quad = lane >> 4, l15 = lane & 15;
  f32x4 acc[4][4] = {};

  if (tid < 128) {
    const float* pf =
        attn_f32 + (size_t)(b * NL + m0 + tid) * NL + 512;
    float s = pf[0] + pf[1] + pf[2] + pf[3] + pf[4] + pf[5] + pf[6] + pf[7];
    inv_lds[tid] = (s > 0.0f) ? 1.0f / s : 0.0f;
  }

  for (int k0 = 0; k0 < NL; k0 += 32) {
    __syncthreads();
#pragma unroll
    for (int i = 0; i < 2; i++) {
      int c = i * 256 + wave * 64 + lane;
      int row = c >> 2, cc = c & 3;
      int sw = (row >> 1) & 3;
      int gc = k0 + ((cc ^ sw) * 8);
      GLD_LDS16(Ap + (size_t)(m0 + row) * ROWU16 + gc,
                As + (size_t)(i * 256 + wave * 64) * 8);
      GLD_LDS16(Bt + (size_t)(d0 + row) * NL + gc,
                Bs + (size_t)(i * 256 + wave * 64) * 8);
    }
    __syncthreads();
    bf16x8 af[4], bfr[4];
#pragma unroll
    for (int t = 0; t < 4; t++) {
      int ra = wm + t * 16 + l15;
      af[t] = *(const bf16x8*)(As + ra * 32 + ((quad ^ ((ra >> 1) & 3)) * 8));
      int rb = wn + t * 16 + l15;
      bfr[t] = *(const bf16x8*)(Bs + rb * 32 + ((quad ^ ((rb >> 1) & 3)) * 8));
    }
#pragma unroll
    for (int tm = 0; tm < 4; tm++)
#pragma unroll
      for (int tn = 0; tn < 4; tn++)
        acc[tm][tn] = __builtin_amdgcn_mfma_f32_16x16x32_bf16(
            af[tm], bfr[tn], acc[tm][tn], 0, 0, 0);
  }

  float* O = out + (size_t)b * NL * ND;
#pragma unroll
  for (int tm = 0; tm < 4; tm++) {
    int rbl = wm + tm * 16 + quad * 4;
#pragma unroll
    for (int tn = 0; tn < 4; tn++) {
      int col = d0 + wn + tn * 16 + l15;
#pragma unroll
      for (int j = 0; j < 4; j++)
        O[(size_t)(m0 + rbl + j) * ND + col] = acc[tm][tn][j] * inv_lds[rbl + j];
    }
  }
}

// ---------------------------------------------------------------------------
// Kernel 3: in-place expand packed bf16 row -> normalized fp32 row.
// One block per attn row; strictly row-local (no cross-block hazard).
// ---------------------------------------------------------------------------
__global__ __launch_bounds__(256) void scale_kernel(float* __restrict__ attn_f32) {
  size_t g = blockIdx.x;
  const uint16_t* u = (const uint16_t*)attn_f32 + g * ROWU16;
  float* f = attn_f32 + g * (size_t)NL;
  int t = threadIdx.x;
  ushort4 h = ((const ushort4*)u)[t];
  float s = f[512] + f[513] + f[514] + f[515] +
            f[516] + f[517] + f[518] + f[519];
  float inv = (s > 0.0f) ? 1.0f / s : 0.0f;
  __syncthreads();  // all reads of the packed row complete before overwrite
  float4 v;
  v.x = bf2f(h.x) * inv; v.y = bf2f(h.y) * inv;
  v.z = bf2f(h.z) * inv; v.w = bf2f(h.w) * inv;
  ((float4*)f)[t] = v;
}

// ---------------------------------------------------------------------------
extern "C" void kernel_launch(void* const* d_in, const int* in_sizes, int n_in,
                              void* d_out, int out_size, void* d_ws,
                              size_t ws_size, hipStream_t stream) {
  (void)in_sizes; (void)n_in; (void)out_size; (void)ws_size;
  const float* q = (const float*)d_in[0];
  float* out = (float*)d_out;
  float* attn = out + (size_t)NB * NL * ND;  // [output | attn] concat
  uint16_t* qb = (uint16_t*)d_ws;            // 16 MiB
  uint16_t* qt = qb + (size_t)NB * NL * ND;  // 16 MiB  (total = 32 MiB, as before)

  convert_kernel<<<dim3(16, 4, NB), 256, 0, stream>>>(q, qb, qt);
  qk_kernel<<<dim3(8, 8, NB), 256, 0, stream>>>(qb, attn);
  pv_kernel<<<dim3(8, 2, NB), 256, 0, stream>>>(attn, qt, out);
  scale_kernel<<<NB * NL, 256, 0, stream>>>(attn);
}